// Round 2
// baseline (5716.100 us; speedup 1.0000x reference)
//
#include <hip/hip_runtime.h>

typedef unsigned int u32;
typedef unsigned short u16;

typedef short short8 __attribute__((ext_vector_type(8)));
typedef float f32x4 __attribute__((ext_vector_type(4)));

// ---------------- numeric helpers ----------------

__device__ __forceinline__ float fast_exp2(float x) {
#if __has_builtin(__builtin_amdgcn_exp2f)
  return __builtin_amdgcn_exp2f(x);
#else
  return exp2f(x);
#endif
}
__device__ __forceinline__ float fast_rcp(float x) {
#if __has_builtin(__builtin_amdgcn_rcpf)
  return __builtin_amdgcn_rcpf(x);
#else
  return 1.0f / x;
#endif
}
__device__ __forceinline__ float sigmf_(float x) {
  return fast_rcp(1.0f + fast_exp2(-1.44269504088896f * x));
}
__device__ __forceinline__ float tanhf_(float x) {
  float e = fast_exp2(2.88539008177793f * x);  // exp(2x)
  return 1.0f - 2.0f * fast_rcp(e + 1.0f);
}
__device__ __forceinline__ u16 f2bf(float x) {
  u32 u = __float_as_uint(x);
  u32 r = (u + 0x7fffu + ((u >> 16) & 1u)) >> 16;
  return (u16)r;
}

#if __has_builtin(__builtin_amdgcn_fdot2_f32_bf16)
typedef __bf16 bf16x2_t __attribute__((ext_vector_type(2)));
__device__ __forceinline__ float dot2bf(u32 w, u32 h, float acc) {
  return __builtin_amdgcn_fdot2_f32_bf16(__builtin_bit_cast(bf16x2_t, w),
                                         __builtin_bit_cast(bf16x2_t, h), acc, false);
}
#else
__device__ __forceinline__ float dot2bf(u32 w, u32 h, float acc) {
  float wl = __uint_as_float(w << 16);
  float wh = __uint_as_float(w & 0xffff0000u);
  float hl = __uint_as_float(h << 16);
  float hh = __uint_as_float(h & 0xffff0000u);
  return fmaf(wh, hh, fmaf(wl, hl, acc));
}
#endif

// ---------------- threefry2x32 (JAX-exact) ----------------

__device__ __forceinline__ void tf_round(u32& x0, u32& x1, int r) {
  x0 += x1;
  x1 = (x1 << r) | (x1 >> (32 - r));
  x1 ^= x0;
}
__device__ void threefry(u32 k0, u32 k1, u32 c0, u32 c1, u32& o0, u32& o1) {
  u32 k2 = k0 ^ k1 ^ 0x1BD11BDAu;
  u32 x0 = c0 + k0, x1 = c1 + k1;
  tf_round(x0, x1, 13); tf_round(x0, x1, 15); tf_round(x0, x1, 26); tf_round(x0, x1, 6);
  x0 += k1; x1 += k2 + 1u;
  tf_round(x0, x1, 17); tf_round(x0, x1, 29); tf_round(x0, x1, 16); tf_round(x0, x1, 24);
  x0 += k2; x1 += k0 + 2u;
  tf_round(x0, x1, 13); tf_round(x0, x1, 15); tf_round(x0, x1, 26); tf_round(x0, x1, 6);
  x0 += k0; x1 += k1 + 3u;
  tf_round(x0, x1, 17); tf_round(x0, x1, 29); tf_round(x0, x1, 16); tf_round(x0, x1, 24);
  x0 += k1; x1 += k2 + 4u;
  tf_round(x0, x1, 13); tf_round(x0, x1, 15); tf_round(x0, x1, 26); tf_round(x0, x1, 6);
  x0 += k2; x1 += k0 + 5u;
  o0 = x0; o1 = x1;
}

#define JAX_PARTITIONABLE 1

// masks layout: [layer(2)][type(3: out,h,c)][b*256+h (16384)]
__global__ void masks_kernel(float* __restrict__ masks) {
  int gid = blockIdx.x * 256 + threadIdx.x;
  if (gid >= 2 * 3 * 16384) return;
  int l = gid / 49152;
  int rem = gid - l * 49152;
  int typ = rem / 16384;
  int i = rem - typ * 16384;
  u32 bits;
#if JAX_PARTITIONABLE
  u32 lk0, lk1, mk0, mk1, y0, y1;
  threefry(0u, 42u, 0u, (u32)l, lk0, lk1);
  threefry(lk0, lk1, 0u, (u32)typ, mk0, mk1);
  threefry(mk0, mk1, 0u, (u32)i, y0, y1);
  bits = y0 ^ y1;
#else
  u32 a0, a1, b0, b1;
  threefry(0u, 42u, 0u, 2u, a0, a1);
  threefry(0u, 42u, 1u, 3u, b0, b1);
  u32 lk0 = (l == 0) ? a0 : a1;
  u32 lk1 = (l == 0) ? b0 : b1;
  u32 e00, e01, e10, e11, e20, e21;
  threefry(lk0, lk1, 0u, 3u, e00, e01);
  threefry(lk0, lk1, 1u, 4u, e10, e11);
  threefry(lk0, lk1, 2u, 5u, e20, e21);
  u32 mk0 = (typ == 0) ? e00 : (typ == 1) ? e20 : e11;
  u32 mk1 = (typ == 0) ? e10 : (typ == 1) ? e01 : e21;
  u32 p = (i < 8192) ? (u32)i : (u32)(i - 8192);
  u32 y0, y1;
  threefry(mk0, mk1, p, p + 8192u, y0, y1);
  bits = (i < 8192) ? y0 : y1;
#endif
  float u = __uint_as_float((bits >> 9) | 0x3f800000u) - 1.0f;
  masks[gid] = (u < 0.75f) ? (1.0f / 0.75f) : 0.0f;
}

// ---------------- prep kernels ----------------

__global__ void conv_bf16(const float* __restrict__ src, u16* __restrict__ dst, int n) {
  int gid = blockIdx.x * 256 + threadIdx.x;
  if (gid < n) dst[gid] = f2bf(src[gid]);
}

// W_hh [1024][256] f32 -> Wp [96 pairs][1024 rows] bf16x2 (register-resident part)
//                         Wst [8 chunks][1024 rows] uint4 (pairs 96+4q..96+4q+3, streamed)
__global__ void pack_whh(const float* __restrict__ W, u32* __restrict__ Wp, u32* __restrict__ Wst) {
  int gid = blockIdx.x * 256 + threadIdx.x;  // 131072
  int p = gid >> 10;
  int row = gid & 1023;
  u32 lo = f2bf(W[row * 256 + 2 * p]);
  u32 hi = f2bf(W[row * 256 + 2 * p + 1]);
  u32 v = lo | (hi << 16);
  if (p < 96) {
    Wp[p * 1024 + row] = v;
  } else {
    int q = (p - 96) >> 2, e = (p - 96) & 3;
    Wst[(q * 1024 + row) * 4 + e] = v;
  }
}

__global__ void add_bias(const float* __restrict__ a, const float* __restrict__ b,
                         float* __restrict__ o, int n) {
  int gid = blockIdx.x * 256 + threadIdx.x;
  if (gid < n) o[gid] = a[gid] + b[gid];
}

// ---------------- input-projection GEMM (bf16 MFMA) ----------------
__global__ __launch_bounds__(256) void gemm_xg(const u16* __restrict__ A,
                                               const u16* __restrict__ Bw,
                                               float* __restrict__ xg) {
  __shared__ uint4 Als[2048];
  __shared__ uint4 Bls[2048];
  int tid = threadIdx.x;
  int m0 = blockIdx.x * 64;
  int n0 = blockIdx.y * 64;
  {
    int row = tid >> 2, kseg = tid & 3;
    const uint4* Ag = (const uint4*)(A + (size_t)(m0 + row) * 256);
    const uint4* Bg = (const uint4*)(Bw + (size_t)(n0 + row) * 256);
#pragma unroll
    for (int uu = 0; uu < 8; ++uu) {
      int kb = kseg * 8 + uu;
      Als[kb * 64 + row] = Ag[kb];
      Bls[kb * 64 + row] = Bg[kb];
    }
  }
  __syncthreads();
  int w = tid >> 6, l = tid & 63;
  int wm = (w >> 1) * 32, wn = (w & 1) * 32;
  int lm = l & 15, q = l >> 4;
  f32x4 acc00 = {0.f, 0.f, 0.f, 0.f}, acc01 = acc00, acc10 = acc00, acc11 = acc00;
#pragma unroll
  for (int ks = 0; ks < 8; ++ks) {
    int kb = ks * 4 + q;
    short8 a0 = __builtin_bit_cast(short8, Als[kb * 64 + wm + lm]);
    short8 a1 = __builtin_bit_cast(short8, Als[kb * 64 + wm + 16 + lm]);
    short8 b0 = __builtin_bit_cast(short8, Bls[kb * 64 + wn + lm]);
    short8 b1 = __builtin_bit_cast(short8, Bls[kb * 64 + wn + 16 + lm]);
    acc00 = __builtin_amdgcn_mfma_f32_16x16x32_bf16(a0, b0, acc00, 0, 0, 0);
    acc01 = __builtin_amdgcn_mfma_f32_16x16x32_bf16(a0, b1, acc01, 0, 0, 0);
    acc10 = __builtin_amdgcn_mfma_f32_16x16x32_bf16(a1, b0, acc10, 0, 0, 0);
    acc11 = __builtin_amdgcn_mfma_f32_16x16x32_bf16(a1, b1, acc11, 0, 0, 0);
  }
#pragma unroll
  for (int fm = 0; fm < 2; ++fm)
#pragma unroll
    for (int fn = 0; fn < 2; ++fn) {
      f32x4 acc = (fm == 0) ? ((fn == 0) ? acc00 : acc01) : ((fn == 0) ? acc10 : acc11);
#pragma unroll
      for (int r = 0; r < 4; ++r) {
        int m = m0 + wm + fm * 16 + q * 4 + r;
        int n = n0 + wn + fn * 16 + lm;
        int bb = m >> 9, tt = m & 511;
        xg[(size_t)tt * 65536 + (size_t)bb * 1024 + n] = acc[r];
      }
    }
}

// ---------------- persistent recurrence v2 ----------------
// One WG (256 threads, 4 waves = 1 wave/SIMD) per batch element.
// Thread `tid` owns the 4 gate rows {tid, tid+256, tid+512, tid+768} = (i,f,g,o)
// of h-index tid: no gate exchange, 1 barrier/step, h double-buffered in LDS.
// W_hh bf16 pairs 0..95 register-resident (384 VGPRs), pairs 96..127 streamed
// from L2 each step (chunk-major coalesced layout).
#define REG_P 96

__global__ __launch_bounds__(256, 1) void lstm_rec(
    const u32* __restrict__ Wp,      // [REG_P][1024]
    const uint4* __restrict__ Wst,   // [8][1024] : pairs 96+4q..96+4q+3 of row r
    const float* __restrict__ xg,    // [512][64][1024]
    const float* __restrict__ bias,  // [1024] (b_ih + b_hh)
    const float* __restrict__ masks, // [3][16384] this layer (out,h,c)
    float* __restrict__ outF,        // layer2: d_out [64][512][256], else null
    u16* __restrict__ outB)          // layer1: bf16 out for next GEMM, else null
{
  __shared__ alignas(16) u16 hbf[2][256];

  const int tid = threadIdx.x;
  const int b = blockIdx.x;

  // register-resident W: 4 rows x 96 pairs
  u32 wreg[4][REG_P];
#pragma unroll
  for (int g = 0; g < 4; ++g) {
    const int row = tid + 256 * g;
#pragma unroll
    for (int p = 0; p < REG_P; ++p) wreg[g][p] = Wp[p * 1024 + row];
  }

  hbf[0][tid] = 0;

  float biasv[4];
#pragma unroll
  for (int g = 0; g < 4; ++g) biasv[g] = bias[tid + 256 * g];

  const float m_out = masks[0 * 16384 + b * 256 + tid];
  const float m_h   = masks[1 * 16384 + b * 256 + tid];
  const float m_c   = masks[2 * 16384 + b * 256 + tid];
  float c = 0.f;

  const float* xgb = xg + b * 1024;
  float* outFb = outF ? outF + (size_t)b * 512 * 256 : (float*)0;
  u16* outBb = outB ? outB + (size_t)b * 512 * 256 : (u16*)0;

  __syncthreads();

  for (int t = 0; t < 512; ++t) {
    // xg loads (HBM/L3) — issue early, consumed at the end
    float xgv[4];
#pragma unroll
    for (int g = 0; g < 4; ++g) xgv[g] = xgb[(size_t)t * 65536 + tid + 256 * g];

    const uint4* h4 = (const uint4*)hbf[t & 1];

    float acc[4];
#pragma unroll
    for (int g = 0; g < 4; ++g) acc[g] = biasv[g];

    // streamed tail prefetch, 2 chunks deep (W is step-invariant; L2-resident)
    uint4 tva[4], tvb[4];
#pragma unroll
    for (int g = 0; g < 4; ++g) tva[g] = Wst[0 * 1024 + tid + 256 * g];

    // register part: pairs 0..95  (h chunks 0..23)
#pragma unroll
    for (int q = 0; q < 24; ++q) {
      uint4 hp = h4[q];
#pragma unroll
      for (int g = 0; g < 4; ++g) {
        acc[g] = dot2bf(wreg[g][4 * q + 0], hp.x, acc[g]);
        acc[g] = dot2bf(wreg[g][4 * q + 1], hp.y, acc[g]);
        acc[g] = dot2bf(wreg[g][4 * q + 2], hp.z, acc[g]);
        acc[g] = dot2bf(wreg[g][4 * q + 3], hp.w, acc[g]);
      }
    }

    // streamed tail: pairs 96..127 (h chunks 24..31)
#pragma unroll
    for (int q = 0; q < 8; ++q) {
      uint4* curv = (q & 1) ? tvb : tva;
      uint4* nxtv = (q & 1) ? tva : tvb;
      if (q < 7) {
#pragma unroll
        for (int g = 0; g < 4; ++g) nxtv[g] = Wst[(q + 1) * 1024 + tid + 256 * g];
      }
      uint4 hp = h4[24 + q];
#pragma unroll
      for (int g = 0; g < 4; ++g) {
        acc[g] = dot2bf(curv[g].x, hp.x, acc[g]);
        acc[g] = dot2bf(curv[g].y, hp.y, acc[g]);
        acc[g] = dot2bf(curv[g].z, hp.z, acc[g]);
        acc[g] = dot2bf(curv[g].w, hp.w, acc[g]);
      }
    }

    float gi = acc[0] + xgv[0];
    float gf = acc[1] + xgv[1];
    float gg = acc[2] + xgv[2];
    float go = acc[3] + xgv[3];
    float fi = sigmf_(gi), ff = sigmf_(gf), fo = sigmf_(go);
    float tg = tanhf_(gg);
    c = ff * c + fi * tg;
    float hn = fo * tanhf_(c);
    float ov = hn * m_out;
    if (outFb) outFb[t * 256 + tid] = ov;
    if (outBb) outBb[t * 256 + tid] = f2bf(ov);
    hbf[(t + 1) & 1][tid] = f2bf(hn * m_h);  // variational h-mask on carry
    c *= m_c;                                // c-mask on carry
    __syncthreads();
  }
}

// ---------------- launch ----------------

extern "C" void kernel_launch(void* const* d_in, const int* in_sizes, int n_in,
                              void* d_out, int out_size, void* d_ws, size_t ws_size,
                              hipStream_t stream) {
  const float* x    = (const float*)d_in[0];
  const float* Wih0 = (const float*)d_in[1];
  const float* Whh0 = (const float*)d_in[2];
  const float* bih0 = (const float*)d_in[3];
  const float* bhh0 = (const float*)d_in[4];
  const float* Wih1 = (const float*)d_in[5];
  const float* Whh1 = (const float*)d_in[6];
  const float* bih1 = (const float*)d_in[7];
  const float* bhh1 = (const float*)d_in[8];
  float* out = (float*)d_out;

  char* w = (char*)d_ws;
  float* masks = (float*)(w + 0);             // 393216 B
  float* biasb = (float*)(w + 393216);        // 8192 B
  u32* Wp0     = (u32*)(w + 401408);          // 393216 B  (96*1024*4)
  u32* Wp1     = (u32*)(w + 794624);          // 393216 B
  u32* Wst0    = (u32*)(w + 1187840);         // 131072 B  (8*1024*16)
  u32* Wst1    = (u32*)(w + 1318912);         // 131072 B
  u16* Wih0b   = (u16*)(w + 1449984);         // 524288 B
  u16* Wih1b   = (u16*)(w + 1974272);         // 524288 B
  u16* xb      = (u16*)(w + 2498560);         // 16777216 B
  u16* o1b     = (u16*)(w + 19275776);        // 16777216 B
  float* xg    = (float*)(w + 36052992);      // 134217728 B (total ~170.3 MB)

  hipLaunchKernelGGL(masks_kernel, dim3(384), dim3(256), 0, stream, masks);
  hipLaunchKernelGGL(conv_bf16, dim3(32768), dim3(256), 0, stream, x, xb, 8388608);
  hipLaunchKernelGGL(conv_bf16, dim3(1024), dim3(256), 0, stream, Wih0, Wih0b, 262144);
  hipLaunchKernelGGL(conv_bf16, dim3(1024), dim3(256), 0, stream, Wih1, Wih1b, 262144);
  hipLaunchKernelGGL(pack_whh, dim3(512), dim3(256), 0, stream, Whh0, Wp0, Wst0);
  hipLaunchKernelGGL(pack_whh, dim3(512), dim3(256), 0, stream, Whh1, Wp1, Wst1);
  hipLaunchKernelGGL(add_bias, dim3(4), dim3(256), 0, stream, bih0, bhh0, biasb, 1024);
  hipLaunchKernelGGL(add_bias, dim3(4), dim3(256), 0, stream, bih1, bhh1, biasb + 1024, 1024);

  // layer 1
  hipLaunchKernelGGL(gemm_xg, dim3(512, 16), dim3(256), 0, stream, xb, Wih0b, xg);
  hipLaunchKernelGGL(lstm_rec, dim3(64), dim3(256), 0, stream, Wp0, (const uint4*)Wst0, xg,
                     biasb, masks, (float*)nullptr, o1b);
  // layer 2
  hipLaunchKernelGGL(gemm_xg, dim3(512, 16), dim3(256), 0, stream, o1b, Wih1b, xg);
  hipLaunchKernelGGL(lstm_rec, dim3(64), dim3(256), 0, stream, Wp1, (const uint4*)Wst1, xg,
                     biasb + 1024, masks + 49152, out, (u16*)nullptr);
}

// Round 3
// 4300.582 us; speedup vs baseline: 1.3291x; 1.3291x over previous
//
#include <hip/hip_runtime.h>

typedef unsigned int u32;
typedef unsigned short u16;

typedef short short8 __attribute__((ext_vector_type(8)));
typedef float f32x4 __attribute__((ext_vector_type(4)));

// ---------------- numeric helpers ----------------

__device__ __forceinline__ float fast_exp2(float x) {
#if __has_builtin(__builtin_amdgcn_exp2f)
  return __builtin_amdgcn_exp2f(x);
#else
  return exp2f(x);
#endif
}
__device__ __forceinline__ float fast_rcp(float x) {
#if __has_builtin(__builtin_amdgcn_rcpf)
  return __builtin_amdgcn_rcpf(x);
#else
  return 1.0f / x;
#endif
}
__device__ __forceinline__ float sigmf_(float x) {
  return fast_rcp(1.0f + fast_exp2(-1.44269504088896f * x));
}
__device__ __forceinline__ float tanhf_(float x) {
  float e = fast_exp2(2.88539008177793f * x);  // exp(2x)
  return 1.0f - 2.0f * fast_rcp(e + 1.0f);
}
__device__ __forceinline__ u16 f2bf(float x) {
  u32 u = __float_as_uint(x);
  u32 r = (u + 0x7fffu + ((u >> 16) & 1u)) >> 16;
  return (u16)r;
}

#if __has_builtin(__builtin_amdgcn_fdot2_f32_bf16)
typedef __bf16 bf16x2_t __attribute__((ext_vector_type(2)));
__device__ __forceinline__ float dot2bf(u32 w, u32 h, float acc) {
  return __builtin_amdgcn_fdot2_f32_bf16(__builtin_bit_cast(bf16x2_t, w),
                                         __builtin_bit_cast(bf16x2_t, h), acc, false);
}
#else
__device__ __forceinline__ float dot2bf(u32 w, u32 h, float acc) {
  float wl = __uint_as_float(w << 16);
  float wh = __uint_as_float(w & 0xffff0000u);
  float hl = __uint_as_float(h << 16);
  float hh = __uint_as_float(h & 0xffff0000u);
  return fmaf(wh, hh, fmaf(wl, hl, acc));
}
#endif

// ---------------- threefry2x32 (JAX-exact) ----------------

__device__ __forceinline__ void tf_round(u32& x0, u32& x1, int r) {
  x0 += x1;
  x1 = (x1 << r) | (x1 >> (32 - r));
  x1 ^= x0;
}
__device__ void threefry(u32 k0, u32 k1, u32 c0, u32 c1, u32& o0, u32& o1) {
  u32 k2 = k0 ^ k1 ^ 0x1BD11BDAu;
  u32 x0 = c0 + k0, x1 = c1 + k1;
  tf_round(x0, x1, 13); tf_round(x0, x1, 15); tf_round(x0, x1, 26); tf_round(x0, x1, 6);
  x0 += k1; x1 += k2 + 1u;
  tf_round(x0, x1, 17); tf_round(x0, x1, 29); tf_round(x0, x1, 16); tf_round(x0, x1, 24);
  x0 += k2; x1 += k0 + 2u;
  tf_round(x0, x1, 13); tf_round(x0, x1, 15); tf_round(x0, x1, 26); tf_round(x0, x1, 6);
  x0 += k0; x1 += k1 + 3u;
  tf_round(x0, x1, 17); tf_round(x0, x1, 29); tf_round(x0, x1, 16); tf_round(x0, x1, 24);
  x0 += k1; x1 += k2 + 4u;
  tf_round(x0, x1, 13); tf_round(x0, x1, 15); tf_round(x0, x1, 26); tf_round(x0, x1, 6);
  x0 += k2; x1 += k0 + 5u;
  o0 = x0; o1 = x1;
}

#define JAX_PARTITIONABLE 1

// masks layout: [layer(2)][type(3: out,h,c)][b*256+h (16384)]
__global__ void masks_kernel(float* __restrict__ masks) {
  int gid = blockIdx.x * 256 + threadIdx.x;
  if (gid >= 2 * 3 * 16384) return;
  int l = gid / 49152;
  int rem = gid - l * 49152;
  int typ = rem / 16384;
  int i = rem - typ * 16384;
  u32 bits;
#if JAX_PARTITIONABLE
  u32 lk0, lk1, mk0, mk1, y0, y1;
  threefry(0u, 42u, 0u, (u32)l, lk0, lk1);
  threefry(lk0, lk1, 0u, (u32)typ, mk0, mk1);
  threefry(mk0, mk1, 0u, (u32)i, y0, y1);
  bits = y0 ^ y1;
#else
  u32 a0, a1, b0, b1;
  threefry(0u, 42u, 0u, 2u, a0, a1);
  threefry(0u, 42u, 1u, 3u, b0, b1);
  u32 lk0 = (l == 0) ? a0 : a1;
  u32 lk1 = (l == 0) ? b0 : b1;
  u32 e00, e01, e10, e11, e20, e21;
  threefry(lk0, lk1, 0u, 3u, e00, e01);
  threefry(lk0, lk1, 1u, 4u, e10, e11);
  threefry(lk0, lk1, 2u, 5u, e20, e21);
  u32 mk0 = (typ == 0) ? e00 : (typ == 1) ? e20 : e11;
  u32 mk1 = (typ == 0) ? e10 : (typ == 1) ? e01 : e21;
  u32 p = (i < 8192) ? (u32)i : (u32)(i - 8192);
  u32 y0, y1;
  threefry(mk0, mk1, p, p + 8192u, y0, y1);
  bits = (i < 8192) ? y0 : y1;
#endif
  float u = __uint_as_float((bits >> 9) | 0x3f800000u) - 1.0f;
  masks[gid] = (u < 0.75f) ? (1.0f / 0.75f) : 0.0f;
}

// ---------------- prep kernels ----------------

__global__ void conv_bf16(const float* __restrict__ src, u16* __restrict__ dst, int n) {
  int gid = blockIdx.x * 256 + threadIdx.x;
  if (gid < n) dst[gid] = f2bf(src[gid]);
}

// W_hh [1024 rows][256 cols] f32 -> Wq [32 chunks][1024 rows] of uint4,
// chunk q of row r = bf16x2 pairs (4q..4q+3), i.e. cols 8q..8q+7.
__global__ void pack_whh(const float* __restrict__ W, u32* __restrict__ Wq) {
  int gid = blockIdx.x * 256 + threadIdx.x;  // 131072 = 128 pairs * 1024 rows
  int p = gid >> 10;
  int row = gid & 1023;
  u32 lo = f2bf(W[row * 256 + 2 * p]);
  u32 hi = f2bf(W[row * 256 + 2 * p + 1]);
  u32 v = lo | (hi << 16);
  int q = p >> 2, e = p & 3;
  Wq[(q * 1024 + row) * 4 + e] = v;
}

__global__ void add_bias(const float* __restrict__ a, const float* __restrict__ b,
                         float* __restrict__ o, int n) {
  int gid = blockIdx.x * 256 + threadIdx.x;
  if (gid < n) o[gid] = a[gid] + b[gid];
}

// ---------------- input-projection GEMM (bf16 MFMA) ----------------
__global__ __launch_bounds__(256) void gemm_xg(const u16* __restrict__ A,
                                               const u16* __restrict__ Bw,
                                               float* __restrict__ xg) {
  __shared__ uint4 Als[2048];
  __shared__ uint4 Bls[2048];
  int tid = threadIdx.x;
  int m0 = blockIdx.x * 64;
  int n0 = blockIdx.y * 64;
  {
    int row = tid >> 2, kseg = tid & 3;
    const uint4* Ag = (const uint4*)(A + (size_t)(m0 + row) * 256);
    const uint4* Bg = (const uint4*)(Bw + (size_t)(n0 + row) * 256);
#pragma unroll
    for (int uu = 0; uu < 8; ++uu) {
      int kb = kseg * 8 + uu;
      Als[kb * 64 + row] = Ag[kb];
      Bls[kb * 64 + row] = Bg[kb];
    }
  }
  __syncthreads();
  int w = tid >> 6, l = tid & 63;
  int wm = (w >> 1) * 32, wn = (w & 1) * 32;
  int lm = l & 15, q = l >> 4;
  f32x4 acc00 = {0.f, 0.f, 0.f, 0.f}, acc01 = acc00, acc10 = acc00, acc11 = acc00;
#pragma unroll
  for (int ks = 0; ks < 8; ++ks) {
    int kb = ks * 4 + q;
    short8 a0 = __builtin_bit_cast(short8, Als[kb * 64 + wm + lm]);
    short8 a1 = __builtin_bit_cast(short8, Als[kb * 64 + wm + 16 + lm]);
    short8 b0 = __builtin_bit_cast(short8, Bls[kb * 64 + wn + lm]);
    short8 b1 = __builtin_bit_cast(short8, Bls[kb * 64 + wn + 16 + lm]);
    acc00 = __builtin_amdgcn_mfma_f32_16x16x32_bf16(a0, b0, acc00, 0, 0, 0);
    acc01 = __builtin_amdgcn_mfma_f32_16x16x32_bf16(a0, b1, acc01, 0, 0, 0);
    acc10 = __builtin_amdgcn_mfma_f32_16x16x32_bf16(a1, b0, acc10, 0, 0, 0);
    acc11 = __builtin_amdgcn_mfma_f32_16x16x32_bf16(a1, b1, acc11, 0, 0, 0);
  }
#pragma unroll
  for (int fm = 0; fm < 2; ++fm)
#pragma unroll
    for (int fn = 0; fn < 2; ++fn) {
      f32x4 acc = (fm == 0) ? ((fn == 0) ? acc00 : acc01) : ((fn == 0) ? acc10 : acc11);
#pragma unroll
      for (int r = 0; r < 4; ++r) {
        int m = m0 + wm + fm * 16 + q * 4 + r;
        int n = n0 + wn + fn * 16 + lm;
        int bb = m >> 9, tt = m & 511;
        xg[(size_t)tt * 65536 + (size_t)bb * 1024 + n] = acc[r];
      }
    }
}

// ---------------- persistent recurrence v3 ----------------
// One WG (1024 threads = 16 waves, 4/SIMD) per batch element.
// Thread tid owns gate row tid (gate = tid>>8, h index = tid&255):
// W/thread = 128 bf16x2 pairs = 128 VGPRs, ~170 total — no spill (256 cap).
// Per step: 32 uniform ds_read_b128 h-broadcasts + 128 v_dot2_f32_bf16,
// gates via LDS, waves 0-3 (one per SIMD) do the pointwise tail. 2 barriers.
__global__ __launch_bounds__(1024, 4) void lstm_rec(
    const uint4* __restrict__ Wq,    // [32][1024] : chunk q, row r
    const float* __restrict__ xg,    // [512][64][1024]
    const float* __restrict__ bias,  // [1024] (b_ih + b_hh)
    const float* __restrict__ masks, // [3][16384] this layer (out,h,c)
    float* __restrict__ outF,        // layer2: d_out [64][512][256], else null
    u16* __restrict__ outB)          // layer1: bf16 out for next GEMM, else null
{
  __shared__ float gates[1024];
  __shared__ alignas(16) u16 hbf[256];

  const int tid = threadIdx.x;
  const int b = blockIdx.x;

  uint4 w[32];
#pragma unroll
  for (int q = 0; q < 32; ++q) w[q] = Wq[q * 1024 + tid];

  if (tid < 256) hbf[tid] = 0;

  const float biasv = bias[tid];
  float c = 0.f, m_out = 0.f, m_h = 0.f, m_c = 0.f;
  if (tid < 256) {
    m_out = masks[0 * 16384 + b * 256 + tid];
    m_h   = masks[1 * 16384 + b * 256 + tid];
    m_c   = masks[2 * 16384 + b * 256 + tid];
  }

  const float* xgp = xg + b * 1024 + tid;
  float* outFp = outF ? outF + (size_t)b * 512 * 256 + tid : (float*)0;
  u16* outBp = outB ? outB + (size_t)b * 512 * 256 + tid : (u16*)0;

  float xg_next = xgp[0];  // prefetch t=0
  __syncthreads();

#pragma unroll 1
  for (int t = 0; t < 512; ++t) {
    float xgv = xg_next;
    if (t < 511) xg_next = xgp[(size_t)(t + 1) * 65536];  // prefetch t+1 (hidden under dot2)

    const uint4* h4 = (const uint4*)hbf;
    float acc = biasv;
#pragma unroll
    for (int q = 0; q < 32; ++q) {
      uint4 hp = h4[q];
      acc = dot2bf(w[q].x, hp.x, acc);
      acc = dot2bf(w[q].y, hp.y, acc);
      acc = dot2bf(w[q].z, hp.z, acc);
      acc = dot2bf(w[q].w, hp.w, acc);
    }
    gates[tid] = acc + xgv;
    __syncthreads();

    if (tid < 256) {
      float gi = gates[tid];
      float gf = gates[tid + 256];
      float gg = gates[tid + 512];
      float go = gates[tid + 768];
      float fi = sigmf_(gi), ff = sigmf_(gf), fo = sigmf_(go);
      float tg = tanhf_(gg);
      c = ff * c + fi * tg;
      float hn = fo * tanhf_(c);
      float ov = hn * m_out;
      if (outFp) outFp[t * 256] = ov;
      if (outBp) outBp[t * 256] = f2bf(ov);
      hbf[tid] = f2bf(hn * m_h);  // variational h-mask on carry
      c *= m_c;                   // c-mask on carry
    }
    __syncthreads();
  }
}

// ---------------- launch ----------------

extern "C" void kernel_launch(void* const* d_in, const int* in_sizes, int n_in,
                              void* d_out, int out_size, void* d_ws, size_t ws_size,
                              hipStream_t stream) {
  const float* x    = (const float*)d_in[0];
  const float* Wih0 = (const float*)d_in[1];
  const float* Whh0 = (const float*)d_in[2];
  const float* bih0 = (const float*)d_in[3];
  const float* bhh0 = (const float*)d_in[4];
  const float* Wih1 = (const float*)d_in[5];
  const float* Whh1 = (const float*)d_in[6];
  const float* bih1 = (const float*)d_in[7];
  const float* bhh1 = (const float*)d_in[8];
  float* out = (float*)d_out;

  char* w = (char*)d_ws;
  float* masks = (float*)(w + 0);             // 393216 B
  float* biasb = (float*)(w + 393216);        // 8192 B
  u32* Wq0     = (u32*)(w + 401408);          // 524288 B  (32*1024*16)
  u32* Wq1     = (u32*)(w + 925696);          // 524288 B
  u16* Wih0b   = (u16*)(w + 1449984);         // 524288 B
  u16* Wih1b   = (u16*)(w + 1974272);         // 524288 B
  u16* xb      = (u16*)(w + 2498560);         // 16777216 B
  u16* o1b     = (u16*)(w + 19275776);        // 16777216 B
  float* xg    = (float*)(w + 36052992);      // 134217728 B (total ~170.3 MB)

  hipLaunchKernelGGL(masks_kernel, dim3(384), dim3(256), 0, stream, masks);
  hipLaunchKernelGGL(conv_bf16, dim3(32768), dim3(256), 0, stream, x, xb, 8388608);
  hipLaunchKernelGGL(conv_bf16, dim3(1024), dim3(256), 0, stream, Wih0, Wih0b, 262144);
  hipLaunchKernelGGL(conv_bf16, dim3(1024), dim3(256), 0, stream, Wih1, Wih1b, 262144);
  hipLaunchKernelGGL(pack_whh, dim3(512), dim3(256), 0, stream, Whh0, Wq0);
  hipLaunchKernelGGL(pack_whh, dim3(512), dim3(256), 0, stream, Whh1, Wq1);
  hipLaunchKernelGGL(add_bias, dim3(4), dim3(256), 0, stream, bih0, bhh0, biasb, 1024);
  hipLaunchKernelGGL(add_bias, dim3(4), dim3(256), 0, stream, bih1, bhh1, biasb + 1024, 1024);

  // layer 1
  hipLaunchKernelGGL(gemm_xg, dim3(512, 16), dim3(256), 0, stream, xb, Wih0b, xg);
  hipLaunchKernelGGL(lstm_rec, dim3(64), dim3(1024), 0, stream, (const uint4*)Wq0, xg,
                     biasb, masks, (float*)nullptr, o1b);
  // layer 2
  hipLaunchKernelGGL(gemm_xg, dim3(512, 16), dim3(256), 0, stream, o1b, Wih1b, xg);
  hipLaunchKernelGGL(lstm_rec, dim3(64), dim3(1024), 0, stream, (const uint4*)Wq1, xg,
                     biasb + 1024, masks + 49152, out, (u16*)nullptr);
}

// Round 4
// 3978.008 us; speedup vs baseline: 1.4369x; 1.0811x over previous
//
#include <hip/hip_runtime.h>

typedef unsigned int u32;
typedef unsigned short u16;

typedef short short8 __attribute__((ext_vector_type(8)));
typedef float f32x4 __attribute__((ext_vector_type(4)));

// ---------------- numeric helpers ----------------

__device__ __forceinline__ float fast_exp2(float x) {
#if __has_builtin(__builtin_amdgcn_exp2f)
  return __builtin_amdgcn_exp2f(x);
#else
  return exp2f(x);
#endif
}
__device__ __forceinline__ float fast_rcp(float x) {
#if __has_builtin(__builtin_amdgcn_rcpf)
  return __builtin_amdgcn_rcpf(x);
#else
  return 1.0f / x;
#endif
}
__device__ __forceinline__ float sigmf_(float x) {
  return fast_rcp(1.0f + fast_exp2(-1.44269504088896f * x));
}
__device__ __forceinline__ float tanhf_(float x) {
  float e = fast_exp2(2.88539008177793f * x);  // exp(2x)
  return 1.0f - 2.0f * fast_rcp(e + 1.0f);
}
__device__ __forceinline__ u16 f2bf(float x) {
  u32 u = __float_as_uint(x);
  u32 r = (u + 0x7fffu + ((u >> 16) & 1u)) >> 16;
  return (u16)r;
}

#if __has_builtin(__builtin_amdgcn_fdot2_f32_bf16)
typedef __bf16 bf16x2_t __attribute__((ext_vector_type(2)));
__device__ __forceinline__ float dot2bf(u32 w, u32 h, float acc) {
  return __builtin_amdgcn_fdot2_f32_bf16(__builtin_bit_cast(bf16x2_t, w),
                                         __builtin_bit_cast(bf16x2_t, h), acc, false);
}
#else
__device__ __forceinline__ float dot2bf(u32 w, u32 h, float acc) {
  float wl = __uint_as_float(w << 16);
  float wh = __uint_as_float(w & 0xffff0000u);
  float hl = __uint_as_float(h << 16);
  float hh = __uint_as_float(h & 0xffff0000u);
  return fmaf(wh, hh, fmaf(wl, hl, acc));
}
#endif

// ---------------- threefry2x32 (JAX-exact) ----------------

__device__ __forceinline__ void tf_round(u32& x0, u32& x1, int r) {
  x0 += x1;
  x1 = (x1 << r) | (x1 >> (32 - r));
  x1 ^= x0;
}
__device__ void threefry(u32 k0, u32 k1, u32 c0, u32 c1, u32& o0, u32& o1) {
  u32 k2 = k0 ^ k1 ^ 0x1BD11BDAu;
  u32 x0 = c0 + k0, x1 = c1 + k1;
  tf_round(x0, x1, 13); tf_round(x0, x1, 15); tf_round(x0, x1, 26); tf_round(x0, x1, 6);
  x0 += k1; x1 += k2 + 1u;
  tf_round(x0, x1, 17); tf_round(x0, x1, 29); tf_round(x0, x1, 16); tf_round(x0, x1, 24);
  x0 += k2; x1 += k0 + 2u;
  tf_round(x0, x1, 13); tf_round(x0, x1, 15); tf_round(x0, x1, 26); tf_round(x0, x1, 6);
  x0 += k0; x1 += k1 + 3u;
  tf_round(x0, x1, 17); tf_round(x0, x1, 29); tf_round(x0, x1, 16); tf_round(x0, x1, 24);
  x0 += k1; x1 += k2 + 4u;
  tf_round(x0, x1, 13); tf_round(x0, x1, 15); tf_round(x0, x1, 26); tf_round(x0, x1, 6);
  x0 += k2; x1 += k0 + 5u;
  o0 = x0; o1 = x1;
}

#define JAX_PARTITIONABLE 1

// masks layout: [layer(2)][type(3: out,h,c)][b*256+h (16384)]
__global__ void masks_kernel(float* __restrict__ masks) {
  int gid = blockIdx.x * 256 + threadIdx.x;
  if (gid >= 2 * 3 * 16384) return;
  int l = gid / 49152;
  int rem = gid - l * 49152;
  int typ = rem / 16384;
  int i = rem - typ * 16384;
  u32 bits;
#if JAX_PARTITIONABLE
  u32 lk0, lk1, mk0, mk1, y0, y1;
  threefry(0u, 42u, 0u, (u32)l, lk0, lk1);
  threefry(lk0, lk1, 0u, (u32)typ, mk0, mk1);
  threefry(mk0, mk1, 0u, (u32)i, y0, y1);
  bits = y0 ^ y1;
#else
  u32 a0, a1, b0, b1;
  threefry(0u, 42u, 0u, 2u, a0, a1);
  threefry(0u, 42u, 1u, 3u, b0, b1);
  u32 lk0 = (l == 0) ? a0 : a1;
  u32 lk1 = (l == 0) ? b0 : b1;
  u32 e00, e01, e10, e11, e20, e21;
  threefry(lk0, lk1, 0u, 3u, e00, e01);
  threefry(lk0, lk1, 1u, 4u, e10, e11);
  threefry(lk0, lk1, 2u, 5u, e20, e21);
  u32 mk0 = (typ == 0) ? e00 : (typ == 1) ? e20 : e11;
  u32 mk1 = (typ == 0) ? e10 : (typ == 1) ? e01 : e21;
  u32 p = (i < 8192) ? (u32)i : (u32)(i - 8192);
  u32 y0, y1;
  threefry(mk0, mk1, p, p + 8192u, y0, y1);
  bits = (i < 8192) ? y0 : y1;
#endif
  float u = __uint_as_float((bits >> 9) | 0x3f800000u) - 1.0f;
  masks[gid] = (u < 0.75f) ? (1.0f / 0.75f) : 0.0f;
}

// ---------------- prep kernels ----------------

__global__ void conv_bf16(const float* __restrict__ src, u16* __restrict__ dst, int n) {
  int gid = blockIdx.x * 256 + threadIdx.x;
  if (gid < n) dst[gid] = f2bf(src[gid]);
}

// W_hh [1024 rows][256 cols] f32 -> Wq [32 chunks][1024 rows] of uint4,
// chunk q of row r = bf16x2 pairs (4q..4q+3), i.e. cols 8q..8q+7.
__global__ void pack_whh(const float* __restrict__ W, u32* __restrict__ Wq) {
  int gid = blockIdx.x * 256 + threadIdx.x;  // 131072 = 128 pairs * 1024 rows
  int p = gid >> 10;
  int row = gid & 1023;
  u32 lo = f2bf(W[row * 256 + 2 * p]);
  u32 hi = f2bf(W[row * 256 + 2 * p + 1]);
  u32 v = lo | (hi << 16);
  int q = p >> 2, e = p & 3;
  Wq[(q * 1024 + row) * 4 + e] = v;
}

__global__ void add_bias(const float* __restrict__ a, const float* __restrict__ b,
                         float* __restrict__ o, int n) {
  int gid = blockIdx.x * 256 + threadIdx.x;
  if (gid < n) o[gid] = a[gid] + b[gid];
}

// ---------------- input-projection GEMM (bf16 MFMA) ----------------
__global__ __launch_bounds__(256) void gemm_xg(const u16* __restrict__ A,
                                               const u16* __restrict__ Bw,
                                               float* __restrict__ xg) {
  __shared__ uint4 Als[2048];
  __shared__ uint4 Bls[2048];
  int tid = threadIdx.x;
  int m0 = blockIdx.x * 64;
  int n0 = blockIdx.y * 64;
  {
    int row = tid >> 2, kseg = tid & 3;
    const uint4* Ag = (const uint4*)(A + (size_t)(m0 + row) * 256);
    const uint4* Bg = (const uint4*)(Bw + (size_t)(n0 + row) * 256);
#pragma unroll
    for (int uu = 0; uu < 8; ++uu) {
      int kb = kseg * 8 + uu;
      Als[kb * 64 + row] = Ag[kb];
      Bls[kb * 64 + row] = Bg[kb];
    }
  }
  __syncthreads();
  int w = tid >> 6, l = tid & 63;
  int wm = (w >> 1) * 32, wn = (w & 1) * 32;
  int lm = l & 15, q = l >> 4;
  f32x4 acc00 = {0.f, 0.f, 0.f, 0.f}, acc01 = acc00, acc10 = acc00, acc11 = acc00;
#pragma unroll
  for (int ks = 0; ks < 8; ++ks) {
    int kb = ks * 4 + q;
    short8 a0 = __builtin_bit_cast(short8, Als[kb * 64 + wm + lm]);
    short8 a1 = __builtin_bit_cast(short8, Als[kb * 64 + wm + 16 + lm]);
    short8 b0 = __builtin_bit_cast(short8, Bls[kb * 64 + wn + lm]);
    short8 b1 = __builtin_bit_cast(short8, Bls[kb * 64 + wn + 16 + lm]);
    acc00 = __builtin_amdgcn_mfma_f32_16x16x32_bf16(a0, b0, acc00, 0, 0, 0);
    acc01 = __builtin_amdgcn_mfma_f32_16x16x32_bf16(a0, b1, acc01, 0, 0, 0);
    acc10 = __builtin_amdgcn_mfma_f32_16x16x32_bf16(a1, b0, acc10, 0, 0, 0);
    acc11 = __builtin_amdgcn_mfma_f32_16x16x32_bf16(a1, b1, acc11, 0, 0, 0);
  }
#pragma unroll
  for (int fm = 0; fm < 2; ++fm)
#pragma unroll
    for (int fn = 0; fn < 2; ++fn) {
      f32x4 acc = (fm == 0) ? ((fn == 0) ? acc00 : acc01) : ((fn == 0) ? acc10 : acc11);
#pragma unroll
      for (int r = 0; r < 4; ++r) {
        int m = m0 + wm + fm * 16 + q * 4 + r;
        int n = n0 + wn + fn * 16 + lm;
        int bb = m >> 9, tt = m & 511;
        xg[(size_t)tt * 65536 + (size_t)bb * 1024 + n] = acc[r];
      }
    }
}

// ---------------- persistent recurrence v4 ----------------
// One WG (512 threads = 8 waves, 2/SIMD) per batch element.
// Thread tid owns gate rows {tid, tid+512}. __launch_bounds__(512,2) -> 256-VGPR
// cap (2 waves/SIMD x 256 = 512-reg pool). W chunks 0..RCH-1 register-resident
// (2 x RCH uint4 = 176 VGPRs); chunks RCH..31 streamed from per-XCD L2 each
// step with a 4-deep rolling prefetch (no LDS-resident W: LDS pipe is
// reserved for the h-broadcast reads). 2 barriers/step.
#define RCH 22
#define SCH (32 - RCH)

__global__ __launch_bounds__(512, 2) void lstm_rec(
    const uint4* __restrict__ Wq,    // [32][1024] chunk-major
    const float* __restrict__ xg,    // [512][64][1024]
    const float* __restrict__ bias,  // [1024] (b_ih + b_hh)
    const float* __restrict__ masks, // [3][16384] this layer (out,h,c)
    float* __restrict__ outF,        // layer2: d_out [64][512][256], else null
    u16* __restrict__ outB)          // layer1: bf16 out for next GEMM, else null
{
  __shared__ float gates[1024];
  __shared__ alignas(16) u16 hbf[256];

  const int tid = threadIdx.x;
  const int b = blockIdx.x;
  const int r0 = tid, r1 = tid + 512;

  uint4 wreg[2][RCH];
#pragma unroll
  for (int cc = 0; cc < RCH; ++cc) {
    wreg[0][cc] = Wq[cc * 1024 + r0];
    wreg[1][cc] = Wq[cc * 1024 + r1];
  }

  if (tid < 256) hbf[tid] = 0;

  const float bias0 = bias[r0];
  const float bias1 = bias[r1];
  float c = 0.f, m_out = 0.f, m_h = 0.f, m_c = 0.f;
  if (tid < 256) {
    m_out = masks[0 * 16384 + b * 256 + tid];
    m_h   = masks[1 * 16384 + b * 256 + tid];
    m_c   = masks[2 * 16384 + b * 256 + tid];
  }

  const float* xgp = xg + b * 1024;
  float* outFp = outF ? outF + (size_t)b * 512 * 256 + tid : (float*)0;
  u16* outBp = outB ? outB + (size_t)b * 512 * 256 + tid : (u16*)0;

  float xgc0 = xgp[r0];  // t=0 prefetch
  float xgc1 = xgp[r1];
  __syncthreads();

#pragma unroll 1
  for (int t = 0; t < 512; ++t) {
    // prefetch xg for t+1 (consumed next iter; in flight for a full step)
    float xgn0 = 0.f, xgn1 = 0.f;
    if (t < 511) {
      xgn0 = xgp[(size_t)(t + 1) * 65536 + r0];
      xgn1 = xgp[(size_t)(t + 1) * 65536 + r1];
    }

    // issue first 4 streamed W chunks (ready after the register dot-loop)
    uint4 tb[4][2];
#pragma unroll
    for (int j = 0; j < 4; ++j) {
      tb[j][0] = Wq[(RCH + j) * 1024 + r0];
      tb[j][1] = Wq[(RCH + j) * 1024 + r1];
    }

    const uint4* h4 = (const uint4*)hbf;
    float acc0 = bias0, acc1 = bias1;
    uint4 hp = h4[0];

    // register-resident part: chunks 0..RCH-1
#pragma unroll
    for (int cc = 0; cc < RCH; ++cc) {
      uint4 hc = hp;
      hp = h4[cc + 1];  // cc+1 <= RCH <= 31: always valid
      acc0 = dot2bf(wreg[0][cc].x, hc.x, acc0);
      acc1 = dot2bf(wreg[1][cc].x, hc.x, acc1);
      acc0 = dot2bf(wreg[0][cc].y, hc.y, acc0);
      acc1 = dot2bf(wreg[1][cc].y, hc.y, acc1);
      acc0 = dot2bf(wreg[0][cc].z, hc.z, acc0);
      acc1 = dot2bf(wreg[1][cc].z, hc.z, acc1);
      acc0 = dot2bf(wreg[0][cc].w, hc.w, acc0);
      acc1 = dot2bf(wreg[1][cc].w, hc.w, acc1);
    }

    // streamed part: chunks RCH..31, 4-deep rolling prefetch
#pragma unroll
    for (int j = 0; j < SCH; ++j) {
      uint4 c0 = tb[j & 3][0];
      uint4 c1 = tb[j & 3][1];
      if (j + 4 < SCH) {
        tb[j & 3][0] = Wq[(RCH + 4 + j) * 1024 + r0];
        tb[j & 3][1] = Wq[(RCH + 4 + j) * 1024 + r1];
      }
      uint4 hc = hp;
      if (RCH + j + 1 < 32) hp = h4[RCH + j + 1];
      acc0 = dot2bf(c0.x, hc.x, acc0);
      acc1 = dot2bf(c1.x, hc.x, acc1);
      acc0 = dot2bf(c0.y, hc.y, acc0);
      acc1 = dot2bf(c1.y, hc.y, acc1);
      acc0 = dot2bf(c0.z, hc.z, acc0);
      acc1 = dot2bf(c1.z, hc.z, acc1);
      acc0 = dot2bf(c0.w, hc.w, acc0);
      acc1 = dot2bf(c1.w, hc.w, acc1);
    }

    gates[r0] = acc0 + xgc0;
    gates[r1] = acc1 + xgc1;
    __syncthreads();

    if (tid < 256) {
      float gi = gates[tid];
      float gf = gates[tid + 256];
      float gg = gates[tid + 512];
      float go = gates[tid + 768];
      float fi = sigmf_(gi), ff = sigmf_(gf), fo = sigmf_(go);
      float tg = tanhf_(gg);
      c = ff * c + fi * tg;
      float hn = fo * tanhf_(c);
      float ov = hn * m_out;
      if (outFp) outFp[t * 256] = ov;
      if (outBp) outBp[t * 256] = f2bf(ov);
      hbf[tid] = f2bf(hn * m_h);  // variational h-mask on carry
      c *= m_c;                   // c-mask on carry
    }
    __syncthreads();

    xgc0 = xgn0;
    xgc1 = xgn1;
  }
}

// ---------------- launch ----------------

extern "C" void kernel_launch(void* const* d_in, const int* in_sizes, int n_in,
                              void* d_out, int out_size, void* d_ws, size_t ws_size,
                              hipStream_t stream) {
  const float* x    = (const float*)d_in[0];
  const float* Wih0 = (const float*)d_in[1];
  const float* Whh0 = (const float*)d_in[2];
  const float* bih0 = (const float*)d_in[3];
  const float* bhh0 = (const float*)d_in[4];
  const float* Wih1 = (const float*)d_in[5];
  const float* Whh1 = (const float*)d_in[6];
  const float* bih1 = (const float*)d_in[7];
  const float* bhh1 = (const float*)d_in[8];
  float* out = (float*)d_out;

  char* w = (char*)d_ws;
  float* masks = (float*)(w + 0);             // 393216 B
  float* biasb = (float*)(w + 393216);        // 8192 B
  u32* Wq0     = (u32*)(w + 401408);          // 524288 B  (32*1024*16)
  u32* Wq1     = (u32*)(w + 925696);          // 524288 B
  u16* Wih0b   = (u16*)(w + 1449984);         // 524288 B
  u16* Wih1b   = (u16*)(w + 1974272);         // 524288 B
  u16* xb      = (u16*)(w + 2498560);         // 16777216 B
  u16* o1b     = (u16*)(w + 19275776);        // 16777216 B
  float* xg    = (float*)(w + 36052992);      // 134217728 B (total ~170.3 MB)

  hipLaunchKernelGGL(masks_kernel, dim3(384), dim3(256), 0, stream, masks);
  hipLaunchKernelGGL(conv_bf16, dim3(32768), dim3(256), 0, stream, x, xb, 8388608);
  hipLaunchKernelGGL(conv_bf16, dim3(1024), dim3(256), 0, stream, Wih0, Wih0b, 262144);
  hipLaunchKernelGGL(conv_bf16, dim3(1024), dim3(256), 0, stream, Wih1, Wih1b, 262144);
  hipLaunchKernelGGL(pack_whh, dim3(512), dim3(256), 0, stream, Whh0, Wq0);
  hipLaunchKernelGGL(pack_whh, dim3(512), dim3(256), 0, stream, Whh1, Wq1);
  hipLaunchKernelGGL(add_bias, dim3(4), dim3(256), 0, stream, bih0, bhh0, biasb, 1024);
  hipLaunchKernelGGL(add_bias, dim3(4), dim3(256), 0, stream, bih1, bhh1, biasb + 1024, 1024);

  // layer 1
  hipLaunchKernelGGL(gemm_xg, dim3(512, 16), dim3(256), 0, stream, xb, Wih0b, xg);
  hipLaunchKernelGGL(lstm_rec, dim3(64), dim3(512), 0, stream, (const uint4*)Wq0, xg,
                     biasb, masks, (float*)nullptr, o1b);
  // layer 2
  hipLaunchKernelGGL(gemm_xg, dim3(512, 16), dim3(256), 0, stream, o1b, Wih1b, xg);
  hipLaunchKernelGGL(lstm_rec, dim3(64), dim3(512), 0, stream, (const uint4*)Wq1, xg,
                     biasb + 1024, masks + 49152, out, (u16*)nullptr);
}